// Round 3
// baseline (402.456 us; speedup 1.0000x reference)
//
#include <hip/hip_runtime.h>

#define N_NODES 50000
#define N_EDGES 1600000
#define F 64
#define G_GRAPHS 64
#define C_CLS 5
#define SLOPE 0.2f

#define NBUCKET ((N_NODES + 127) >> 7)   // 391 buckets of 128 nodes
#define ACHUNK 2048
#define NCHUNKS ((N_EDGES + ACHUNK - 1) / ACHUNK)
#define CAP 8192                          // max edges per bucket (mean 4092, std 64)
#define MAXCH 4                           // reg-cached chunks: degree <= 256 fast path

__device__ __forceinline__ float lrelu(float x) { return fmaxf(x, SLOPE * x); }

// ---------------- CSR build: bucketed counting sort ----------------

__global__ __launch_bounds__(256) void bucket_count(const int* __restrict__ dst,
                                                    int* __restrict__ gcount) {
    __shared__ int hist[NBUCKET];
    int tid = threadIdx.x;
    for (int i = tid; i < NBUCKET; i += 256) hist[i] = 0;
    __syncthreads();
    int base = blockIdx.x * ACHUNK;
    int lim = min(ACHUNK, N_EDGES - base);
    for (int t = tid; t < lim; t += 256) atomicAdd(&hist[dst[base + t] >> 7], 1);
    __syncthreads();
    for (int i = tid; i < NBUCKET; i += 256)
        if (hist[i]) atomicAdd(&gcount[i], hist[i]);
}

__global__ __launch_bounds__(512) void scan_buckets(const int* __restrict__ gcount,
                                                    int* __restrict__ bucket_base) {
    __shared__ int sc[512];
    int tid = threadIdx.x;
    int v = (tid < NBUCKET) ? gcount[tid] : 0;
    sc[tid] = v;
    __syncthreads();
    for (int s = 1; s < 512; s <<= 1) {
        int t = (tid >= s) ? sc[tid - s] : 0;
        __syncthreads();
        sc[tid] += t;
        __syncthreads();
    }
    if (tid < NBUCKET) bucket_base[tid] = sc[tid] - v;   // exclusive
}

__global__ __launch_bounds__(256) void bucket_scatter(
    const int* __restrict__ src, const int* __restrict__ dst,
    const int* __restrict__ bucket_base, int* __restrict__ gcursor,
    unsigned long long* __restrict__ bedges) {
    __shared__ int hist[NBUCKET];
    __shared__ int resv[NBUCKET];
    __shared__ int cur[NBUCKET];
    int tid = threadIdx.x;
    for (int i = tid; i < NBUCKET; i += 256) { hist[i] = 0; cur[i] = 0; }
    __syncthreads();
    int base = blockIdx.x * ACHUNK;
    int lim = min(ACHUNK, N_EDGES - base);
    for (int t = tid; t < lim; t += 256) atomicAdd(&hist[dst[base + t] >> 7], 1);
    __syncthreads();
    for (int i = tid; i < NBUCKET; i += 256)
        if (hist[i]) resv[i] = atomicAdd(&gcursor[i], hist[i]);
    __syncthreads();
    for (int t = tid; t < lim; t += 256) {
        int e = base + t;
        int d = dst[e];
        int b = d >> 7;
        int r = atomicAdd(&cur[b], 1);
        bedges[bucket_base[b] + resv[b] + r] =
            ((unsigned long long)(unsigned)(d & 127) << 32) | (unsigned)src[e];
    }
}

__global__ __launch_bounds__(256) void bucket_csr(
    const unsigned long long* __restrict__ bedges, const int* __restrict__ gcount,
    const int* __restrict__ bucket_base, int* __restrict__ row_ptr,
    int* __restrict__ csr_src) {
    __shared__ int hist[128];
    __shared__ int sc[128];
    __shared__ int loff[129];
    __shared__ int cur[128];
    __shared__ int outs[CAP];
    int tid = threadIdx.x;
    int b = blockIdx.x;
    int nbase = b << 7;
    int nlocal = min(128, N_NODES - nbase);
    int cnt = min(gcount[b], CAP);
    int cbase = bucket_base[b];
    if (tid < 128) { hist[tid] = 0; cur[tid] = 0; }
    __syncthreads();
    for (int t = tid; t < cnt; t += 256)
        atomicAdd(&hist[(int)(bedges[cbase + t] >> 32)], 1);
    __syncthreads();
    if (tid < 128) sc[tid] = hist[tid];
    __syncthreads();
    for (int s = 1; s < 128; s <<= 1) {
        int t = (tid < 128 && tid >= s) ? sc[tid - s] : 0;
        __syncthreads();
        if (tid < 128) sc[tid] += t;
        __syncthreads();
    }
    if (tid < 128) loff[tid + 1] = sc[tid];
    if (tid == 0) loff[0] = 0;
    __syncthreads();
    for (int t = tid; t < cnt; t += 256) {
        unsigned long long p = bedges[cbase + t];
        int dl = (int)(p >> 32);
        int r = atomicAdd(&cur[dl], 1);
        outs[loff[dl] + r] = (int)(unsigned)p;
    }
    __syncthreads();
    for (int t = tid; t < cnt; t += 256) csr_src[cbase + t] = outs[t];
    for (int i = tid; i < nlocal; i += 256) row_ptr[nbase + i] = cbase + loff[i];
    if (b == NBUCKET - 1 && tid == 0) row_ptr[N_NODES] = cbase + loff[nlocal];
}

// ---------------- fused GEMM + attention dots ----------------
// H = X @ W ; S = H @ a_s ; D = H @ a_d   (wave = row, lane = feature)

__global__ __launch_bounds__(256) void gemm_sd_kernel(
    const float* __restrict__ X, const float* __restrict__ W,
    const float* __restrict__ a_s, const float* __restrict__ a_d,
    float* __restrict__ H, float* __restrict__ S, float* __restrict__ D) {
    __shared__ float Wl[F * F];
    __shared__ float as_l[F], ad_l[F];
    for (int i = threadIdx.x; i < F * F; i += 256) Wl[i] = W[i];
    if (threadIdx.x < F) { as_l[threadIdx.x] = a_s[threadIdx.x]; ad_l[threadIdx.x] = a_d[threadIdx.x]; }
    __syncthreads();
    int lane = threadIdx.x & 63;
    int wid  = threadIdx.x >> 6;
    int gw   = blockIdx.x * 4 + wid;
    int nw   = gridDim.x * 4;
    for (int r = gw; r < N_NODES; r += nw) {
        float x = X[r * F + lane];
        float acc = 0.f;
        #pragma unroll
        for (int k = 0; k < F; k++) {
            float xk = __shfl(x, k, 64);
            acc = fmaf(xk, Wl[k * F + lane], acc);
        }
        H[r * F + lane] = acc;
        float sv = acc * as_l[lane];
        float dv = acc * ad_l[lane];
        #pragma unroll
        for (int o = 32; o > 0; o >>= 1) {
            sv += __shfl_down(sv, o, 64);
            dv += __shfl_down(dv, o, 64);
        }
        if (lane == 0) { S[r] = sv; D[r] = dv; }
    }
}

// ---------------- per-node softmax aggregation ----------------
// one wave per node; edge-per-lane scores+exp, shfl-broadcast fma loop

__global__ __launch_bounds__(256) void agg_kernel(
    const float* __restrict__ H, const float* __restrict__ S, const float* __restrict__ Dv,
    const int* __restrict__ row_ptr, const int* __restrict__ csr_src,
    const float* __restrict__ bias, float* __restrict__ OUT) {
    int lane = threadIdx.x & 63;
    int i = (blockIdx.x * blockDim.x + threadIdx.x) >> 6;
    if (i >= N_NODES) return;
    int start = row_ptr[i], end = row_ptr[i + 1];
    int deg = end - start;
    float d_i = Dv[i];
    float eself = lrelu(S[i] + d_i);
    float acc, z;
    int nch = (deg + 63) >> 6;

    if (nch <= MAXCH) {
        // ---- fast path: cache src & score in registers ----
        int   sj_reg[MAXCH];
        float e_reg[MAXCH];
        float m = eself;
        #pragma unroll
        for (int c = 0; c < MAXCH; c++) {
            int j = start + (c << 6) + lane;
            bool v = (c < nch) && (j < end);
            int sj = v ? csr_src[j] : 0;
            float e = v ? lrelu(S[sj] + d_i) : -1e30f;
            sj_reg[c] = sj;
            e_reg[c] = e;
            m = fmaxf(m, e);
        }
        #pragma unroll
        for (int o = 32; o > 0; o >>= 1) m = fmaxf(m, __shfl_xor(m, o, 64));
        float pself = __expf(eself - m);
        float zlane = 0.f;
        acc = pself * H[i * F + lane];
        #pragma unroll
        for (int c = 0; c < MAXCH; c++) {
            if (c >= nch) break;
            float p = __expf(e_reg[c] - m);   // invalid lanes: e=-1e30 -> p=0
            zlane += p;
            int cnt = min(64, deg - (c << 6));
            #pragma unroll 4
            for (int t = 0; t < cnt; t++) {
                float pj  = __shfl(p, t, 64);
                int   sjt = __shfl(sj_reg[c], t, 64);
                acc = fmaf(pj, H[sjt * F + lane], acc);
            }
        }
        #pragma unroll
        for (int o = 32; o > 0; o >>= 1) zlane += __shfl_xor(zlane, o, 64);
        z = zlane + pself;
    } else {
        // ---- rare fallback (degree > 256): two-pass recompute ----
        float m = eself;
        for (int j = start + lane; j < end; j += 64) {
            float e = lrelu(S[csr_src[j]] + d_i);
            m = fmaxf(m, e);
        }
        #pragma unroll
        for (int o = 32; o > 0; o >>= 1) m = fmaxf(m, __shfl_xor(m, o, 64));
        float pself = __expf(eself - m);
        float zlane = 0.f;
        acc = pself * H[i * F + lane];
        for (int cb = start; cb < end; cb += 64) {
            int j = cb + lane;
            bool v = j < end;
            int sj = v ? csr_src[j] : 0;
            float p = v ? __expf(lrelu(S[sj] + d_i) - m) : 0.f;
            zlane += p;
            int cnt = min(64, end - cb);
            for (int t = 0; t < cnt; t++) {
                float pj  = __shfl(p, t, 64);
                int   sjt = __shfl(sj, t, 64);
                acc = fmaf(pj, H[sjt * F + lane], acc);
            }
        }
        #pragma unroll
        for (int o = 32; o > 0; o >>= 1) zlane += __shfl_xor(zlane, o, 64);
        z = zlane + pself;
    }
    float o = acc / z + bias[lane];
    OUT[i * F + lane] = fmaxf(o, 0.f);  // both layers have ReLU after
}

// ---------------- global max pool (batch is sorted) ----------------

__global__ __launch_bounds__(256) void pool_kernel(
    const float* __restrict__ H, const int* __restrict__ batch, float* __restrict__ gmax) {
    int lane = threadIdx.x & 63;
    int gw = (blockIdx.x * blockDim.x + threadIdx.x) >> 6;
    int nw = (gridDim.x * blockDim.x) >> 6;
    int per = (N_NODES + nw - 1) / nw;
    int s = gw * per;
    int e = min(N_NODES, s + per);
    if (s >= e) return;
    int curb = batch[s];
    float mx = H[s * F + lane];
    for (int i = s + 1; i < e; i++) {
        int b = batch[i];
        float v = H[i * F + lane];
        if (b != curb) {
            atomicMax((int*)&gmax[curb * F + lane], __float_as_int(mx));
            curb = b; mx = v;
        } else {
            mx = fmaxf(mx, v);
        }
    }
    atomicMax((int*)&gmax[curb * F + lane], __float_as_int(mx));
}

// ---------------- final linear ----------------

__global__ void final_kernel(const float* __restrict__ gmax, const float* __restrict__ Wl,
                             const float* __restrict__ bl, float* __restrict__ out) {
    int g = blockIdx.x;
    int c = threadIdx.x;
    if (c < C_CLS) {
        float acc = bl[c];
        #pragma unroll
        for (int f = 0; f < F; f++) acc = fmaf(gmax[g * F + f], Wl[f * C_CLS + c], acc);
        out[g * C_CLS + c] = acc;
    }
}

// ---------------- launch ----------------

extern "C" void kernel_launch(void* const* d_in, const int* in_sizes, int n_in,
                              void* d_out, int out_size, void* d_ws, size_t ws_size,
                              hipStream_t stream) {
    const float* x    = (const float*)d_in[0];
    const int*   ei   = (const int*)d_in[1];
    const int*   batch= (const int*)d_in[2];
    const float* W1   = (const float*)d_in[3];
    const float* a1s  = (const float*)d_in[4];
    const float* a1d  = (const float*)d_in[5];
    const float* b1   = (const float*)d_in[6];
    const float* W2   = (const float*)d_in[7];
    const float* a2s  = (const float*)d_in[8];
    const float* a2d  = (const float*)d_in[9];
    const float* b2   = (const float*)d_in[10];
    const float* Wl   = (const float*)d_in[11];
    const float* bl   = (const float*)d_in[12];
    float* out = (float*)d_out;

    const int* src = ei;
    const int* dst = ei + N_EDGES;

    // workspace layout (256B aligned)
    char* ws = (char*)d_ws;
    size_t off = 0;
    auto alloc = [&](size_t bytes) { size_t o = off; off += (bytes + 255) & ~(size_t)255; return o; };
    int*   row_ptr = (int*)(ws + alloc((size_t)(N_NODES + 1) * 4));
    int*   csr_src = (int*)(ws + alloc((size_t)N_EDGES * 4));
    // bedges (E*8 = 12.8MB) aliases hA (N*F*4 = 12.8MB): bedges is dead before hA is first written
    char*  hAbed   = ws + alloc((size_t)N_EDGES * 8);
    unsigned long long* bedges = (unsigned long long*)hAbed;
    float* hA      = (float*)hAbed;
    float* hB      = (float*)(ws + alloc((size_t)N_NODES * F * 4));
    float* Sv      = (float*)(ws + alloc((size_t)N_NODES * 4));
    float* Dv      = (float*)(ws + alloc((size_t)N_NODES * 4));
    float* gmax    = (float*)(ws + alloc((size_t)G_GRAPHS * F * 4));
    int*   bmeta   = (int*)(ws + alloc((size_t)3 * NBUCKET * 4));
    int*   gcount  = bmeta;
    int*   gcursor = bmeta + NBUCKET;
    int*   bucket_base = bmeta + 2 * NBUCKET;

    // ---- CSR build (bucketed counting sort) ----
    hipMemsetAsync(bmeta, 0, (size_t)2 * NBUCKET * 4, stream);
    bucket_count<<<NCHUNKS, 256, 0, stream>>>(dst, gcount);
    scan_buckets<<<1, 512, 0, stream>>>(gcount, bucket_base);
    bucket_scatter<<<NCHUNKS, 256, 0, stream>>>(src, dst, bucket_base, gcursor, bedges);
    bucket_csr<<<NBUCKET, 256, 0, stream>>>(bedges, gcount, bucket_base, row_ptr, csr_src);

    // ---- layer 1 ----
    gemm_sd_kernel<<<1024, 256, 0, stream>>>(x, W1, a1s, a1d, hA, Sv, Dv);
    agg_kernel<<<(N_NODES * 64 + 255) / 256, 256, 0, stream>>>(hA, Sv, Dv, row_ptr, csr_src, b1, hB);

    // ---- layer 2 ----
    gemm_sd_kernel<<<1024, 256, 0, stream>>>(hB, W2, a2s, a2d, hA, Sv, Dv);
    agg_kernel<<<(N_NODES * 64 + 255) / 256, 256, 0, stream>>>(hA, Sv, Dv, row_ptr, csr_src, b2, hB);

    // ---- pool + classifier ----
    hipMemsetAsync(gmax, 0, (size_t)G_GRAPHS * F * 4, stream);
    pool_kernel<<<512, 256, 0, stream>>>(hB, batch, gmax);
    final_kernel<<<G_GRAPHS, 64, 0, stream>>>(gmax, Wl, bl, out);
}

// Round 4
// 321.636 us; speedup vs baseline: 1.2513x; 1.2513x over previous
//
#include <hip/hip_runtime.h>

#define N_NODES 50000
#define N_EDGES 1600000
#define F 64
#define G_GRAPHS 64
#define C_CLS 5
#define SLOPE 0.2f

#define NBUCKET ((N_NODES + 127) >> 7)   // 391 buckets of 128 nodes
#define ACHUNK 2048
#define NCHUNKS ((N_EDGES + ACHUNK - 1) / ACHUNK)
#define CAP 8192                          // max edges per bucket (mean 4092, std 64)
#define MAXCH 4                           // reg-cached chunks: degree <= 256 fast path

__device__ __forceinline__ float lrelu(float x) { return fmaxf(x, SLOPE * x); }

// ---------------- CSR build: bucketed counting sort ----------------

__global__ __launch_bounds__(256) void bucket_count(const int* __restrict__ dst,
                                                    int* __restrict__ gcount) {
    __shared__ int hist[NBUCKET];
    int tid = threadIdx.x;
    for (int i = tid; i < NBUCKET; i += 256) hist[i] = 0;
    __syncthreads();
    int base = blockIdx.x * ACHUNK;
    int lim = min(ACHUNK, N_EDGES - base);
    for (int t = tid; t < lim; t += 256) atomicAdd(&hist[dst[base + t] >> 7], 1);
    __syncthreads();
    for (int i = tid; i < NBUCKET; i += 256)
        if (hist[i]) atomicAdd(&gcount[i], hist[i]);
}

__global__ __launch_bounds__(512) void scan_buckets(const int* __restrict__ gcount,
                                                    int* __restrict__ bucket_base) {
    __shared__ int sc[512];
    int tid = threadIdx.x;
    int v = (tid < NBUCKET) ? gcount[tid] : 0;
    sc[tid] = v;
    __syncthreads();
    for (int s = 1; s < 512; s <<= 1) {
        int t = (tid >= s) ? sc[tid - s] : 0;
        __syncthreads();
        sc[tid] += t;
        __syncthreads();
    }
    if (tid < NBUCKET) bucket_base[tid] = sc[tid] - v;   // exclusive
}

__global__ __launch_bounds__(256) void bucket_scatter(
    const int* __restrict__ src, const int* __restrict__ dst,
    const int* __restrict__ bucket_base, int* __restrict__ gcursor,
    unsigned long long* __restrict__ bedges) {
    __shared__ int hist[NBUCKET];
    __shared__ int resv[NBUCKET];
    __shared__ int cur[NBUCKET];
    int tid = threadIdx.x;
    for (int i = tid; i < NBUCKET; i += 256) { hist[i] = 0; cur[i] = 0; }
    __syncthreads();
    int base = blockIdx.x * ACHUNK;
    int lim = min(ACHUNK, N_EDGES - base);
    for (int t = tid; t < lim; t += 256) atomicAdd(&hist[dst[base + t] >> 7], 1);
    __syncthreads();
    for (int i = tid; i < NBUCKET; i += 256)
        if (hist[i]) resv[i] = atomicAdd(&gcursor[i], hist[i]);
    __syncthreads();
    for (int t = tid; t < lim; t += 256) {
        int e = base + t;
        int d = dst[e];
        int b = d >> 7;
        int r = atomicAdd(&cur[b], 1);
        bedges[bucket_base[b] + resv[b] + r] =
            ((unsigned long long)(unsigned)(d & 127) << 32) | (unsigned)src[e];
    }
}

__global__ __launch_bounds__(256) void bucket_csr(
    const unsigned long long* __restrict__ bedges, const int* __restrict__ gcount,
    const int* __restrict__ bucket_base, int* __restrict__ row_ptr,
    int* __restrict__ csr_src) {
    __shared__ int hist[128];
    __shared__ int sc[128];
    __shared__ int loff[129];
    __shared__ int cur[128];
    __shared__ int outs[CAP];
    int tid = threadIdx.x;
    int b = blockIdx.x;
    int nbase = b << 7;
    int nlocal = min(128, N_NODES - nbase);
    int cnt = min(gcount[b], CAP);
    int cbase = bucket_base[b];
    if (tid < 128) { hist[tid] = 0; cur[tid] = 0; }
    __syncthreads();
    for (int t = tid; t < cnt; t += 256)
        atomicAdd(&hist[(int)(bedges[cbase + t] >> 32)], 1);
    __syncthreads();
    if (tid < 128) sc[tid] = hist[tid];
    __syncthreads();
    for (int s = 1; s < 128; s <<= 1) {
        int t = (tid < 128 && tid >= s) ? sc[tid - s] : 0;
        __syncthreads();
        if (tid < 128) sc[tid] += t;
        __syncthreads();
    }
    if (tid < 128) loff[tid + 1] = sc[tid];
    if (tid == 0) loff[0] = 0;
    __syncthreads();
    for (int t = tid; t < cnt; t += 256) {
        unsigned long long p = bedges[cbase + t];
        int dl = (int)(p >> 32);
        int r = atomicAdd(&cur[dl], 1);
        outs[loff[dl] + r] = (int)(unsigned)p;
    }
    __syncthreads();
    for (int t = tid; t < cnt; t += 256) csr_src[cbase + t] = outs[t];
    for (int i = tid; i < nlocal; i += 256) row_ptr[nbase + i] = cbase + loff[i];
    if (b == NBUCKET - 1 && tid == 0) row_ptr[N_NODES] = cbase + loff[nlocal];
}

// ---------------- fused GEMM + attention dots ----------------
// H = X @ W ; S = H @ a_s ; D = H @ a_d   (wave = row, lane = feature)

__global__ __launch_bounds__(256) void gemm_sd_kernel(
    const float* __restrict__ X, const float* __restrict__ W,
    const float* __restrict__ a_s, const float* __restrict__ a_d,
    float* __restrict__ H, float* __restrict__ S, float* __restrict__ D) {
    __shared__ float Wl[F * F];
    __shared__ float as_l[F], ad_l[F];
    for (int i = threadIdx.x; i < F * F; i += 256) Wl[i] = W[i];
    if (threadIdx.x < F) { as_l[threadIdx.x] = a_s[threadIdx.x]; ad_l[threadIdx.x] = a_d[threadIdx.x]; }
    __syncthreads();
    int lane = threadIdx.x & 63;
    int wid  = threadIdx.x >> 6;
    int gw   = blockIdx.x * 4 + wid;
    int nw   = gridDim.x * 4;
    for (int r = gw; r < N_NODES; r += nw) {
        float x = X[r * F + lane];
        float acc = 0.f;
        #pragma unroll
        for (int k = 0; k < F; k++) {
            float xk = __shfl(x, k, 64);
            acc = fmaf(xk, Wl[k * F + lane], acc);
        }
        H[r * F + lane] = acc;
        float sv = acc * as_l[lane];
        float dv = acc * ad_l[lane];
        #pragma unroll
        for (int o = 32; o > 0; o >>= 1) {
            sv += __shfl_down(sv, o, 64);
            dv += __shfl_down(dv, o, 64);
        }
        if (lane == 0) { S[r] = sv; D[r] = dv; }
    }
}

// ---------------- per-node softmax aggregation ----------------
// wave = node; 4 edge-slots x 16 lanes, float4 per lane -> 4 source rows
// fetched per wave-wide load instruction (4x the memory-level parallelism)

__global__ __launch_bounds__(256) void agg_kernel(
    const float* __restrict__ H, const float* __restrict__ S, const float* __restrict__ Dv,
    const int* __restrict__ row_ptr, const int* __restrict__ csr_src,
    const float* __restrict__ bias, float* __restrict__ OUT) {
    int lane = threadIdx.x & 63;
    int i = (blockIdx.x * blockDim.x + threadIdx.x) >> 6;
    if (i >= N_NODES) return;
    int start = row_ptr[i], end = row_ptr[i + 1];
    int deg = end - start;
    int nch = (deg + 63) >> 6;
    float d_i = Dv[i];
    float eself = lrelu(S[i] + d_i);
    int g  = lane >> 4;          // edge-slot group 0..3
    int fl = (lane & 15) << 2;   // feature base (float4 per lane)
    float ax = 0.f, ay = 0.f, az = 0.f, aw = 0.f;
    float z;

    if (nch <= MAXCH) {
        // ---- fast path: cache src & p in registers ----
        int   sj_reg[MAXCH];
        float p_reg[MAXCH];
        float m = eself;
        #pragma unroll
        for (int c = 0; c < MAXCH; c++) {
            int j = start + (c << 6) + lane;
            bool v = (c < nch) && (j < end);
            int sj = v ? csr_src[j] : 0;
            float e = v ? lrelu(S[sj] + d_i) : -1e30f;
            sj_reg[c] = sj;
            p_reg[c] = e;                 // score for now
            m = fmaxf(m, e);
        }
        #pragma unroll
        for (int o = 32; o > 0; o >>= 1) m = fmaxf(m, __shfl_xor(m, o, 64));
        float zlane = 0.f;
        #pragma unroll
        for (int c = 0; c < MAXCH; c++) {
            if (c < nch) {
                float p = __expf(p_reg[c] - m);   // invalid lanes: e=-1e30 -> 0
                p_reg[c] = p;
                zlane += p;
            }
        }
        #pragma unroll
        for (int o = 32; o > 0; o >>= 1) zlane += __shfl_xor(zlane, o, 64);
        float pself = __expf(eself - m);
        z = zlane + pself;
        float4 h4 = *(const float4*)&H[i * F + fl];
        if (g == 0) { ax = pself * h4.x; ay = pself * h4.y; az = pself * h4.z; aw = pself * h4.w; }
        #pragma unroll
        for (int c = 0; c < MAXCH; c++) {
            if (c >= nch) break;
            int cnt = min(64, deg - (c << 6));
            int iters = (cnt + 3) >> 2;
            #pragma unroll 2
            for (int t = 0; t < iters; t++) {
                int slot = (t << 2) + g;
                float pj = __shfl(p_reg[c], slot, 64);
                int  sjt = __shfl(sj_reg[c], slot, 64);
                float4 hh = *(const float4*)&H[sjt * F + fl];
                ax = fmaf(pj, hh.x, ax);
                ay = fmaf(pj, hh.y, ay);
                az = fmaf(pj, hh.z, az);
                aw = fmaf(pj, hh.w, aw);
            }
        }
    } else {
        // ---- rare fallback (degree > 256): streaming chunks ----
        float m = eself;
        for (int j = start + lane; j < end; j += 64)
            m = fmaxf(m, lrelu(S[csr_src[j]] + d_i));
        #pragma unroll
        for (int o = 32; o > 0; o >>= 1) m = fmaxf(m, __shfl_xor(m, o, 64));
        float pself = __expf(eself - m);
        float zlane = 0.f;
        float4 h4 = *(const float4*)&H[i * F + fl];
        if (g == 0) { ax = pself * h4.x; ay = pself * h4.y; az = pself * h4.z; aw = pself * h4.w; }
        for (int cb = start; cb < end; cb += 64) {
            int j = cb + lane;
            bool v = j < end;
            int sj = v ? csr_src[j] : 0;
            float p = v ? __expf(lrelu(S[sj] + d_i) - m) : 0.f;
            zlane += p;
            int cnt = min(64, end - cb);
            int iters = (cnt + 3) >> 2;
            for (int t = 0; t < iters; t++) {
                int slot = (t << 2) + g;
                float pj = __shfl(p, slot, 64);
                int  sjt = __shfl(sj, slot, 64);
                float4 hh = *(const float4*)&H[sjt * F + fl];
                ax = fmaf(pj, hh.x, ax);
                ay = fmaf(pj, hh.y, ay);
                az = fmaf(pj, hh.z, az);
                aw = fmaf(pj, hh.w, aw);
            }
        }
        #pragma unroll
        for (int o = 32; o > 0; o >>= 1) zlane += __shfl_xor(zlane, o, 64);
        z = zlane + pself;
    }
    if (nch <= MAXCH) {
        // z butterfly already done in fast path? (zlane reduced before use)
    }
    // cross-group reduction: combine the 4 edge-slot partial sums
    #pragma unroll
    for (int o = 16; o <= 32; o <<= 1) {
        ax += __shfl_xor(ax, o, 64);
        ay += __shfl_xor(ay, o, 64);
        az += __shfl_xor(az, o, 64);
        aw += __shfl_xor(aw, o, 64);
    }
    if (g == 0) {
        float4 b4 = *(const float4*)&bias[fl];
        float4 o4;
        o4.x = fmaxf(ax / z + b4.x, 0.f);
        o4.y = fmaxf(ay / z + b4.y, 0.f);
        o4.z = fmaxf(az / z + b4.z, 0.f);
        o4.w = fmaxf(aw / z + b4.w, 0.f);
        *(float4*)&OUT[i * F + fl] = o4;   // both layers have ReLU after
    }
}

// ---------------- global max pool (batch is sorted) ----------------

__global__ __launch_bounds__(256) void pool_kernel(
    const float* __restrict__ H, const int* __restrict__ batch, float* __restrict__ gmax) {
    int lane = threadIdx.x & 63;
    int gw = (blockIdx.x * blockDim.x + threadIdx.x) >> 6;
    int nw = (gridDim.x * blockDim.x) >> 6;
    int per = (N_NODES + nw - 1) / nw;
    int s = gw * per;
    int e = min(N_NODES, s + per);
    if (s >= e) return;
    int curb = batch[s];
    float mx = H[s * F + lane];
    for (int i = s + 1; i < e; i++) {
        int b = batch[i];
        float v = H[i * F + lane];
        if (b != curb) {
            atomicMax((int*)&gmax[curb * F + lane], __float_as_int(mx));
            curb = b; mx = v;
        } else {
            mx = fmaxf(mx, v);
        }
    }
    atomicMax((int*)&gmax[curb * F + lane], __float_as_int(mx));
}

// ---------------- final linear ----------------

__global__ void final_kernel(const float* __restrict__ gmax, const float* __restrict__ Wl,
                             const float* __restrict__ bl, float* __restrict__ out) {
    int g = blockIdx.x;
    int c = threadIdx.x;
    if (c < C_CLS) {
        float acc = bl[c];
        #pragma unroll
        for (int f = 0; f < F; f++) acc = fmaf(gmax[g * F + f], Wl[f * C_CLS + c], acc);
        out[g * C_CLS + c] = acc;
    }
}

// ---------------- launch ----------------

extern "C" void kernel_launch(void* const* d_in, const int* in_sizes, int n_in,
                              void* d_out, int out_size, void* d_ws, size_t ws_size,
                              hipStream_t stream) {
    const float* x    = (const float*)d_in[0];
    const int*   ei   = (const int*)d_in[1];
    const int*   batch= (const int*)d_in[2];
    const float* W1   = (const float*)d_in[3];
    const float* a1s  = (const float*)d_in[4];
    const float* a1d  = (const float*)d_in[5];
    const float* b1   = (const float*)d_in[6];
    const float* W2   = (const float*)d_in[7];
    const float* a2s  = (const float*)d_in[8];
    const float* a2d  = (const float*)d_in[9];
    const float* b2   = (const float*)d_in[10];
    const float* Wl   = (const float*)d_in[11];
    const float* bl   = (const float*)d_in[12];
    float* out = (float*)d_out;

    const int* src = ei;
    const int* dst = ei + N_EDGES;

    // workspace layout (256B aligned)
    char* ws = (char*)d_ws;
    size_t off = 0;
    auto alloc = [&](size_t bytes) { size_t o = off; off += (bytes + 255) & ~(size_t)255; return o; };
    int*   row_ptr = (int*)(ws + alloc((size_t)(N_NODES + 1) * 4));
    int*   csr_src = (int*)(ws + alloc((size_t)N_EDGES * 4));
    // bedges (E*8 = 12.8MB) aliases hA (N*F*4 = 12.8MB): bedges is dead before hA is first written
    char*  hAbed   = ws + alloc((size_t)N_EDGES * 8);
    unsigned long long* bedges = (unsigned long long*)hAbed;
    float* hA      = (float*)hAbed;
    float* hB      = (float*)(ws + alloc((size_t)N_NODES * F * 4));
    float* Sv      = (float*)(ws + alloc((size_t)N_NODES * 4));
    float* Dv      = (float*)(ws + alloc((size_t)N_NODES * 4));
    float* gmax    = (float*)(ws + alloc((size_t)G_GRAPHS * F * 4));
    int*   bmeta   = (int*)(ws + alloc((size_t)3 * NBUCKET * 4));
    int*   gcount  = bmeta;
    int*   gcursor = bmeta + NBUCKET;
    int*   bucket_base = bmeta + 2 * NBUCKET;

    // ---- CSR build (bucketed counting sort) ----
    hipMemsetAsync(bmeta, 0, (size_t)2 * NBUCKET * 4, stream);
    bucket_count<<<NCHUNKS, 256, 0, stream>>>(dst, gcount);
    scan_buckets<<<1, 512, 0, stream>>>(gcount, bucket_base);
    bucket_scatter<<<NCHUNKS, 256, 0, stream>>>(src, dst, bucket_base, gcursor, bedges);
    bucket_csr<<<NBUCKET, 256, 0, stream>>>(bedges, gcount, bucket_base, row_ptr, csr_src);

    // ---- layer 1 ----
    gemm_sd_kernel<<<1024, 256, 0, stream>>>(x, W1, a1s, a1d, hA, Sv, Dv);
    agg_kernel<<<(N_NODES * 64 + 255) / 256, 256, 0, stream>>>(hA, Sv, Dv, row_ptr, csr_src, b1, hB);

    // ---- layer 2 ----
    gemm_sd_kernel<<<1024, 256, 0, stream>>>(hB, W2, a2s, a2d, hA, Sv, Dv);
    agg_kernel<<<(N_NODES * 64 + 255) / 256, 256, 0, stream>>>(hA, Sv, Dv, row_ptr, csr_src, b2, hB);

    // ---- pool + classifier ----
    hipMemsetAsync(gmax, 0, (size_t)G_GRAPHS * F * 4, stream);
    pool_kernel<<<512, 256, 0, stream>>>(hB, batch, gmax);
    final_kernel<<<G_GRAPHS, 64, 0, stream>>>(gmax, Wl, bl, out);
}

// Round 6
// 279.586 us; speedup vs baseline: 1.4395x; 1.1504x over previous
//
#include <hip/hip_runtime.h>

#define N_NODES 50000
#define N_EDGES 1600000
#define F 64
#define G_GRAPHS 64
#define C_CLS 5
#define SLOPE 0.2f

#define NBUCKET ((N_NODES + 127) >> 7)   // 391 buckets of 128 nodes
#define ACHUNK 4096
#define NCHUNKS ((N_EDGES + ACHUNK - 1) / ACHUNK)   // 391
#define CAP 8192                          // max edges per bucket (mean 4092, std 64)
#define MAXCH 4                           // reg-cached chunks: degree <= 256 fast path

__device__ __forceinline__ float lrelu(float x) { return fmaxf(x, SLOPE * x); }

// ---------------- CSR build: deterministic bucketed counting sort ----------------
// Cmat[chunk][bucket] counts; Coff[bucket][chunk] = exact global segment start.

__global__ __launch_bounds__(256) void count_matrix(const int* __restrict__ dst,
                                                    int* __restrict__ Cmat,
                                                    int* __restrict__ gcount) {
    __shared__ int hist[NBUCKET];
    int tid = threadIdx.x;
    int c = blockIdx.x;
    for (int i = tid; i < NBUCKET; i += 256) hist[i] = 0;
    __syncthreads();
    int base = c * ACHUNK;
    int lim = min(ACHUNK, N_EDGES - base);
    for (int t = tid; t < lim; t += 256) atomicAdd(&hist[dst[base + t] >> 7], 1);
    __syncthreads();
    for (int i = tid; i < NBUCKET; i += 256) {
        int h = hist[i];
        Cmat[c * NBUCKET + i] = h;            // coalesced per block
        if (h) atomicAdd(&gcount[i], h);
    }
}

__global__ __launch_bounds__(512) void scan_buckets(const int* __restrict__ gcount,
                                                    int* __restrict__ bucket_base) {
    __shared__ int sc[512];
    int tid = threadIdx.x;
    int v = (tid < NBUCKET) ? gcount[tid] : 0;
    sc[tid] = v;
    __syncthreads();
    for (int s = 1; s < 512; s <<= 1) {
        int t = (tid >= s) ? sc[tid - s] : 0;
        __syncthreads();
        sc[tid] += t;
        __syncthreads();
    }
    if (tid < NBUCKET) bucket_base[tid] = sc[tid] - v;   // exclusive
}

// one block per bucket b: exclusive scan of Cmat[.][b] across chunks
__global__ __launch_bounds__(512) void scan_chunk_offsets(const int* __restrict__ Cmat,
                                                          const int* __restrict__ bucket_base,
                                                          int* __restrict__ Coff) {
    __shared__ int sc[512];
    int tid = threadIdx.x;
    int b = blockIdx.x;
    int v = (tid < NCHUNKS) ? Cmat[tid * NBUCKET + b] : 0;
    sc[tid] = v;
    __syncthreads();
    for (int s = 1; s < 512; s <<= 1) {
        int t = (tid >= s) ? sc[tid - s] : 0;
        __syncthreads();
        sc[tid] += t;
        __syncthreads();
    }
    if (tid < NCHUNKS) Coff[b * NCHUNKS + tid] = bucket_base[b] + sc[tid] - v;
}

// chunk-local LDS counting sort with deterministic destinations, linear flush
__global__ __launch_bounds__(512) void bucket_scatter(
    const int* __restrict__ src, const int* __restrict__ dst,
    const int* __restrict__ Coff, unsigned long long* __restrict__ bedges) {
    __shared__ int hist[NBUCKET];
    __shared__ int cur[NBUCKET];
    __shared__ int dloc[NBUCKET];   // Coff[b][c] - loff[b]
    __shared__ int sc[512];
    __shared__ unsigned long long stage[ACHUNK];
    int tid = threadIdx.x;
    int c = blockIdx.x;
    int base = c * ACHUNK;
    int lim = min(ACHUNK, N_EDGES - base);
    for (int i = tid; i < NBUCKET; i += 512) hist[i] = 0;
    __syncthreads();
    // pass 1: histogram buckets
    for (int t = tid; t < lim; t += 512) atomicAdd(&hist[dst[base + t] >> 7], 1);
    __syncthreads();
    // block-wide exclusive scan of the bucket counts -> local offsets
    int v = (tid < NBUCKET) ? hist[tid] : 0;
    sc[tid] = v;
    __syncthreads();
    for (int s = 1; s < 512; s <<= 1) {
        int t = (tid >= s) ? sc[tid - s] : 0;
        __syncthreads();
        sc[tid] += t;
        __syncthreads();
    }
    if (tid < NBUCKET) {
        int loff = sc[tid] - v;
        cur[tid] = loff;                            // placement cursor
        dloc[tid] = Coff[tid * NCHUNKS + c] - loff; // global = dloc + stage pos
    }
    __syncthreads();
    // pass 2: place edges bucket-sorted into LDS staging (L2-hot re-read)
    for (int t = tid; t < lim; t += 512) {
        int d = dst[base + t];
        int pos = atomicAdd(&cur[d >> 7], 1);
        stage[pos] = ((unsigned long long)(unsigned)d << 32) | (unsigned)src[base + t];
    }
    __syncthreads();
    // linear flush: consecutive threads -> consecutive addresses per segment
    for (int t = tid; t < lim; t += 512) {
        unsigned long long p = stage[t];
        int d = (int)(p >> 32);
        bedges[dloc[d >> 7] + t] =
            ((unsigned long long)(unsigned)(d & 127) << 32) | (p & 0xffffffffull);
    }
}

__global__ __launch_bounds__(256) void bucket_csr(
    const unsigned long long* __restrict__ bedges, const int* __restrict__ gcount,
    const int* __restrict__ bucket_base, int* __restrict__ row_ptr,
    int* __restrict__ csr_src) {
    __shared__ int hist[128];
    __shared__ int sc[128];
    __shared__ int loff[129];
    __shared__ int cur[128];
    __shared__ int outs[CAP];
    int tid = threadIdx.x;
    int b = blockIdx.x;
    int nbase = b << 7;
    int nlocal = min(128, N_NODES - nbase);
    int cnt = min(gcount[b], CAP);
    int cbase = bucket_base[b];
    if (tid < 128) { hist[tid] = 0; cur[tid] = 0; }
    __syncthreads();
    for (int t = tid; t < cnt; t += 256)
        atomicAdd(&hist[(int)(bedges[cbase + t] >> 32)], 1);
    __syncthreads();
    if (tid < 128) sc[tid] = hist[tid];
    __syncthreads();
    for (int s = 1; s < 128; s <<= 1) {
        int t = (tid < 128 && tid >= s) ? sc[tid - s] : 0;
        __syncthreads();
        if (tid < 128) sc[tid] += t;
        __syncthreads();
    }
    if (tid < 128) loff[tid + 1] = sc[tid];
    if (tid == 0) loff[0] = 0;
    __syncthreads();
    for (int t = tid; t < cnt; t += 256) {
        unsigned long long p = bedges[cbase + t];
        int dl = (int)(p >> 32);
        int r = atomicAdd(&cur[dl], 1);
        outs[loff[dl] + r] = (int)(unsigned)p;
    }
    __syncthreads();
    for (int t = tid; t < cnt; t += 256) csr_src[cbase + t] = outs[t];
    for (int i = tid; i < nlocal; i += 256) row_ptr[nbase + i] = cbase + loff[i];
    if (b == NBUCKET - 1 && tid == 0) row_ptr[N_NODES] = cbase + loff[nlocal];
}

// ---------------- fused GEMM + attention dots ----------------
// H = X @ W ; S = H @ a_s ; D = H @ a_d   (wave = row, lane = feature)

__global__ __launch_bounds__(256) void gemm_sd_kernel(
    const float* __restrict__ X, const float* __restrict__ W,
    const float* __restrict__ a_s, const float* __restrict__ a_d,
    float* __restrict__ H, float* __restrict__ S, float* __restrict__ D) {
    __shared__ float Wl[F * F];
    __shared__ float as_l[F], ad_l[F];
    for (int i = threadIdx.x; i < F * F; i += 256) Wl[i] = W[i];
    if (threadIdx.x < F) { as_l[threadIdx.x] = a_s[threadIdx.x]; ad_l[threadIdx.x] = a_d[threadIdx.x]; }
    __syncthreads();
    int lane = threadIdx.x & 63;
    int wid  = threadIdx.x >> 6;
    int gw   = blockIdx.x * 4 + wid;
    int nw   = gridDim.x * 4;
    for (int r = gw; r < N_NODES; r += nw) {
        float x = X[r * F + lane];
        float acc = 0.f;
        #pragma unroll
        for (int k = 0; k < F; k++) {
            float xk = __shfl(x, k, 64);
            acc = fmaf(xk, Wl[k * F + lane], acc);
        }
        H[r * F + lane] = acc;
        float sv = acc * as_l[lane];
        float dv = acc * ad_l[lane];
        #pragma unroll
        for (int o = 32; o > 0; o >>= 1) {
            sv += __shfl_down(sv, o, 64);
            dv += __shfl_down(dv, o, 64);
        }
        if (lane == 0) { S[r] = sv; D[r] = dv; }
    }
}

// ---------------- per-node softmax aggregation ----------------
// wave = node; 4 edge-slots x 16 lanes, float4 per lane -> 4 source rows
// fetched per wave-wide load instruction (4x the memory-level parallelism)

__global__ __launch_bounds__(256) void agg_kernel(
    const float* __restrict__ H, const float* __restrict__ S, const float* __restrict__ Dv,
    const int* __restrict__ row_ptr, const int* __restrict__ csr_src,
    const float* __restrict__ bias, float* __restrict__ OUT) {
    int lane = threadIdx.x & 63;
    int i = (blockIdx.x * blockDim.x + threadIdx.x) >> 6;
    if (i >= N_NODES) return;
    int start = row_ptr[i], end = row_ptr[i + 1];
    int deg = end - start;
    int nch = (deg + 63) >> 6;
    float d_i = Dv[i];
    float eself = lrelu(S[i] + d_i);
    int g  = lane >> 4;          // edge-slot group 0..3
    int fl = (lane & 15) << 2;   // feature base (float4 per lane)
    float ax = 0.f, ay = 0.f, az = 0.f, aw = 0.f;
    float z;

    if (nch <= MAXCH) {
        // ---- fast path: cache src & p in registers ----
        int   sj_reg[MAXCH];
        float p_reg[MAXCH];
        float m = eself;
        #pragma unroll
        for (int c = 0; c < MAXCH; c++) {
            int j = start + (c << 6) + lane;
            bool v = (c < nch) && (j < end);
            int sj = v ? csr_src[j] : 0;
            float e = v ? lrelu(S[sj] + d_i) : -1e30f;
            sj_reg[c] = sj;
            p_reg[c] = e;                 // score for now
            m = fmaxf(m, e);
        }
        #pragma unroll
        for (int o = 32; o > 0; o >>= 1) m = fmaxf(m, __shfl_xor(m, o, 64));
        float zlane = 0.f;
        #pragma unroll
        for (int c = 0; c < MAXCH; c++) {
            if (c < nch) {
                float p = __expf(p_reg[c] - m);   // invalid lanes: e=-1e30 -> 0
                p_reg[c] = p;
                zlane += p;
            }
        }
        #pragma unroll
        for (int o = 32; o > 0; o >>= 1) zlane += __shfl_xor(zlane, o, 64);
        float pself = __expf(eself - m);
        z = zlane + pself;
        float4 h4 = *(const float4*)&H[i * F + fl];
        if (g == 0) { ax = pself * h4.x; ay = pself * h4.y; az = pself * h4.z; aw = pself * h4.w; }
        #pragma unroll
        for (int c = 0; c < MAXCH; c++) {
            if (c >= nch) break;
            int cnt = min(64, deg - (c << 6));
            int iters = (cnt + 3) >> 2;
            #pragma unroll 2
            for (int t = 0; t < iters; t++) {
                int slot = (t << 2) + g;
                float pj = __shfl(p_reg[c], slot, 64);
                int  sjt = __shfl(sj_reg[c], slot, 64);
                float4 hh = *(const float4*)&H[sjt * F + fl];
                ax = fmaf(pj, hh.x, ax);
                ay = fmaf(pj, hh.y, ay);
                az = fmaf(pj, hh.z, az);
                aw = fmaf(pj, hh.w, aw);
            }
        }
    } else {
        // ---- rare fallback (degree > 256): streaming chunks ----
        float m = eself;
        for (int j = start + lane; j < end; j += 64)
            m = fmaxf(m, lrelu(S[csr_src[j]] + d_i));
        #pragma unroll
        for (int o = 32; o > 0; o >>= 1) m = fmaxf(m, __shfl_xor(m, o, 64));
        float pself = __expf(eself - m);
        float zlane = 0.f;
        float4 h4 = *(const float4*)&H[i * F + fl];
        if (g == 0) { ax = pself * h4.x; ay = pself * h4.y; az = pself * h4.z; aw = pself * h4.w; }
        for (int cb = start; cb < end; cb += 64) {
            int j = cb + lane;
            bool v = j < end;
            int sj = v ? csr_src[j] : 0;
            float p = v ? __expf(lrelu(S[sj] + d_i) - m) : 0.f;
            zlane += p;
            int cnt = min(64, end - cb);
            int iters = (cnt + 3) >> 2;
            for (int t = 0; t < iters; t++) {
                int slot = (t << 2) + g;
                float pj = __shfl(p, slot, 64);
                int  sjt = __shfl(sj, slot, 64);
                float4 hh = *(const float4*)&H[sjt * F + fl];
                ax = fmaf(pj, hh.x, ax);
                ay = fmaf(pj, hh.y, ay);
                az = fmaf(pj, hh.z, az);
                aw = fmaf(pj, hh.w, aw);
            }
        }
        #pragma unroll
        for (int o = 32; o > 0; o >>= 1) zlane += __shfl_xor(zlane, o, 64);
        z = zlane + pself;
    }
    // cross-group reduction: combine the 4 edge-slot partial sums
    #pragma unroll
    for (int o = 16; o <= 32; o <<= 1) {
        ax += __shfl_xor(ax, o, 64);
        ay += __shfl_xor(ay, o, 64);
        az += __shfl_xor(az, o, 64);
        aw += __shfl_xor(aw, o, 64);
    }
    if (g == 0) {
        float4 b4 = *(const float4*)&bias[fl];
        float4 o4;
        o4.x = fmaxf(ax / z + b4.x, 0.f);
        o4.y = fmaxf(ay / z + b4.y, 0.f);
        o4.z = fmaxf(az / z + b4.z, 0.f);
        o4.w = fmaxf(aw / z + b4.w, 0.f);
        *(float4*)&OUT[i * F + fl] = o4;   // both layers have ReLU after
    }
}

// ---------------- global max pool (batch is sorted) ----------------

__global__ __launch_bounds__(256) void pool_kernel(
    const float* __restrict__ H, const int* __restrict__ batch, float* __restrict__ gmax) {
    int lane = threadIdx.x & 63;
    int gw = (blockIdx.x * blockDim.x + threadIdx.x) >> 6;
    int nw = (gridDim.x * blockDim.x) >> 6;
    int per = (N_NODES + nw - 1) / nw;
    int s = gw * per;
    int e = min(N_NODES, s + per);
    if (s >= e) return;
    int curb = batch[s];
    float mx = H[s * F + lane];
    for (int i = s + 1; i < e; i++) {
        int b = batch[i];
        float v = H[i * F + lane];
        if (b != curb) {
            atomicMax((int*)&gmax[curb * F + lane], __float_as_int(mx));
            curb = b; mx = v;
        } else {
            mx = fmaxf(mx, v);
        }
    }
    atomicMax((int*)&gmax[curb * F + lane], __float_as_int(mx));
}

// ---------------- final linear ----------------

__global__ void final_kernel(const float* __restrict__ gmax, const float* __restrict__ Wl,
                             const float* __restrict__ bl, float* __restrict__ out) {
    int g = blockIdx.x;
    int c = threadIdx.x;
    if (c < C_CLS) {
        float acc = bl[c];
        #pragma unroll
        for (int f = 0; f < F; f++) acc = fmaf(gmax[g * F + f], Wl[f * C_CLS + c], acc);
        out[g * C_CLS + c] = acc;
    }
}

// ---------------- launch ----------------

extern "C" void kernel_launch(void* const* d_in, const int* in_sizes, int n_in,
                              void* d_out, int out_size, void* d_ws, size_t ws_size,
                              hipStream_t stream) {
    const float* x    = (const float*)d_in[0];
    const int*   ei   = (const int*)d_in[1];
    const int*   batch= (const int*)d_in[2];
    const float* W1   = (const float*)d_in[3];
    const float* a1s  = (const float*)d_in[4];
    const float* a1d  = (const float*)d_in[5];
    const float* b1   = (const float*)d_in[6];
    const float* W2   = (const float*)d_in[7];
    const float* a2s  = (const float*)d_in[8];
    const float* a2d  = (const float*)d_in[9];
    const float* b2   = (const float*)d_in[10];
    const float* Wl   = (const float*)d_in[11];
    const float* bl   = (const float*)d_in[12];
    float* out = (float*)d_out;

    const int* src = ei;
    const int* dst = ei + N_EDGES;

    // workspace layout (256B aligned)
    char* ws = (char*)d_ws;
    size_t off = 0;
    auto alloc = [&](size_t bytes) { size_t o = off; off += (bytes + 255) & ~(size_t)255; return o; };
    int*   row_ptr = (int*)(ws + alloc((size_t)(N_NODES + 1) * 4));
    int*   csr_src = (int*)(ws + alloc((size_t)N_EDGES * 4));
    // bedges (E*8 = 12.8MB) aliases hA (N*F*4 = 12.8MB): bedges dead before hA written
    char*  hAbed   = ws + alloc((size_t)N_EDGES * 8);
    unsigned long long* bedges = (unsigned long long*)hAbed;
    float* hA      = (float*)hAbed;
    // Cmat/Coff (611KB each) alias hB: CSR build completes before hB first written
    char*  hBc     = ws + alloc((size_t)N_NODES * F * 4);
    float* hB      = (float*)hBc;
    int*   Cmat    = (int*)hBc;
    int*   Coff    = (int*)(hBc + ((size_t)NCHUNKS * NBUCKET * 4 + 255 & ~(size_t)255));
    float* Sv      = (float*)(ws + alloc((size_t)N_NODES * 4));
    float* Dv      = (float*)(ws + alloc((size_t)N_NODES * 4));
    float* gmax    = (float*)(ws + alloc((size_t)G_GRAPHS * F * 4));
    int*   bmeta   = (int*)(ws + alloc((size_t)2 * NBUCKET * 4));
    int*   gcount  = bmeta;
    int*   bucket_base = bmeta + NBUCKET;

    // ---- CSR build (deterministic bucketed counting sort) ----
    hipMemsetAsync(gcount, 0, (size_t)NBUCKET * 4, stream);
    count_matrix<<<NCHUNKS, 256, 0, stream>>>(dst, Cmat, gcount);
    scan_buckets<<<1, 512, 0, stream>>>(gcount, bucket_base);
    scan_chunk_offsets<<<NBUCKET, 512, 0, stream>>>(Cmat, bucket_base, Coff);
    bucket_scatter<<<NCHUNKS, 512, 0, stream>>>(src, dst, Coff, bedges);
    bucket_csr<<<NBUCKET, 256, 0, stream>>>(bedges, gcount, bucket_base, row_ptr, csr_src);

    // ---- layer 1 ----
    gemm_sd_kernel<<<1024, 256, 0, stream>>>(x, W1, a1s, a1d, hA, Sv, Dv);
    agg_kernel<<<(N_NODES * 64 + 255) / 256, 256, 0, stream>>>(hA, Sv, Dv, row_ptr, csr_src, b1, hB);

    // ---- layer 2 ----
    gemm_sd_kernel<<<1024, 256, 0, stream>>>(hB, W2, a2s, a2d, hA, Sv, Dv);
    agg_kernel<<<(N_NODES * 64 + 255) / 256, 256, 0, stream>>>(hA, Sv, Dv, row_ptr, csr_src, b2, hB);

    // ---- pool + classifier ----
    hipMemsetAsync(gmax, 0, (size_t)G_GRAPHS * F * 4, stream);
    pool_kernel<<<512, 256, 0, stream>>>(hB, batch, gmax);
    final_kernel<<<G_GRAPHS, 64, 0, stream>>>(gmax, Wl, bl, out);
}